// Round 6
// baseline (238.828 us; speedup 1.0000x reference)
//
#include <hip/hip_runtime.h>

// BRNN integrate one-hot: h_t = clip(h_{t-1} @ fsa[tok_t], -10, 10)
// B=64 L=512 S=128 V=10000, fsa = U[0,1) (non-negative by problem spec).
//
// clip(+10) is absorbing: h2 saturates to all-10s; it stays there for every
// token whose matrix has min column-sum >= 1. fsa >= 0 => a PARTIAL column
// sum >= 1 soundly lower-bounds the full column sum. Two-stage adaptive cert
// (rows 0..6, escalate to rows 0..12 for ~2.5% of matrices).
//
// SINGLE fused kernel (grid = V+B blocks):
//   blocks 0..V-1 : spread 10.0-fill of out[:,2:,:] + adaptive cert
//                   -> minok[v], then release fetch_add on done-counter
//   blocks V..    : exact t=0,1 head for batch b; acquire-spin until counter==V;
//                   check own tokens vs minok; exact full scan only on failure.
// Only 64 blocks ever wait (<< co-residency capacity) and cert blocks never
// wait -> forward progress guaranteed for any dispatch order. Visibility via
// device-scope release/acquire (Guideline 16).

constexpr int S_DIM = 128;
constexpr int L_DIM = 512;
constexpr int B_DIM = 64;
constexpr int V_DIM = 10000;
constexpr int CR1   = 7;          // stage-1 certificate rows
constexpr int CR2   = 13;         // total rows after escalation
constexpr int NT    = 512;
constexpr int RG    = NT / 32;
constexpr int RPG   = S_DIM / RG;
constexpr int PER_B      = (L_DIM - 2) * S_DIM / 4;        // 16320 float4 per batch
constexpr int FILL_TOTAL = PER_B * B_DIM;                  // 1044480 float4
constexpr int FPB        = (FILL_TOTAL + V_DIM - 1) / V_DIM; // 105 float4/block

typedef float f4 __attribute__((ext_vector_type(4)));

__global__ __launch_bounds__(512)
void brnn_fused(const float* __restrict__ fsa, const int* __restrict__ tokens,
                int* __restrict__ minok, int* __restrict__ counter,
                float* __restrict__ out) {
    const int tid = threadIdx.x;
    __shared__ float4 cpart[CR2][32];
    __shared__ float  h1[S_DIM];
    __shared__ float  hpart[4][S_DIM];
    __shared__ int    esc, bad, sat;

    if (blockIdx.x < V_DIM) {
        // ================= cert block =================
        const int v = blockIdx.x;
        if (tid == 0) { esc = 0; bad = 0; }

        // spread saturated fill: out[:, 2:, :] = 10.0 (105 contiguous float4/block)
        {
            const int i = v * FPB + tid;
            if (tid < FPB && i < FILL_TOTAL) {
                const int bb = i / PER_B;
                const int r  = i - bb * PER_B;
                f4* p = reinterpret_cast<f4*>(out + (size_t)bb * (L_DIM * S_DIM) + 2 * S_DIM);
                const f4 ten = {10.f, 10.f, 10.f, 10.f};
                __builtin_nontemporal_store(ten, p + r);
            }
        }

        const float* M = fsa + (size_t)v * (S_DIM * S_DIM);

        // stage 1: rows 0..CR1-1
        if (tid < CR1 * 32) {
            const int rg = tid >> 5;
            const int c4 = tid & 31;
            cpart[rg][c4] = *reinterpret_cast<const float4*>(M + rg * S_DIM + c4 * 4);
        }
        __syncthreads();

        float4 s;                            // live in tid<32 only
        if (tid < 32) {
            s = cpart[0][tid];
            #pragma unroll
            for (int g = 1; g < CR1; ++g) {
                float4 p = cpart[g][tid];
                s.x += p.x; s.y += p.y; s.z += p.z; s.w += p.w;
            }
            float mn = fminf(fminf(s.x, s.y), fminf(s.z, s.w));
            if (mn < 1.0f) esc = 1;          // set-to-1 race: benign
        }
        __syncthreads();

        if (esc) {                           // block-uniform branch
            if (tid < (CR2 - CR1) * 32) {
                const int rg = CR1 + (tid >> 5);
                const int c4 = tid & 31;
                cpart[rg][c4] = *reinterpret_cast<const float4*>(M + rg * S_DIM + c4 * 4);
            }
            __syncthreads();
            if (tid < 32) {
                #pragma unroll
                for (int g = CR1; g < CR2; ++g) {
                    float4 p = cpart[g][tid];
                    s.x += p.x; s.y += p.y; s.z += p.z; s.w += p.w;
                }
                float mn = fminf(fminf(s.x, s.y), fminf(s.z, s.w));
                if (mn < 1.0f) bad = 1;      // set-to-1 race: benign
            }
            __syncthreads();
        }
        if (tid == 0) {
            minok[v] = !bad;                 // plain store, ordered by release RMW below
            __hip_atomic_fetch_add(counter, 1, __ATOMIC_RELEASE, __HIP_MEMORY_SCOPE_AGENT);
        }
    } else {
        // ================= head block (one batch) =================
        const int b = blockIdx.x - V_DIM;
        const int j = tid & 127;
        const int q = tid >> 7;
        const int* btok = tokens + b * L_DIM;
        float* bout = out + (size_t)b * (L_DIM * S_DIM);

        if (tid == 0) sat = 1;

        const float* M0 = fsa + (size_t)btok[0] * (S_DIM * S_DIM);
        const float* M1 = fsa + (size_t)btok[1] * (S_DIM * S_DIM);

        // t = 0: h1 = clip(row 0 of M0)
        if (q == 0) {
            float v0 = fminf(fmaxf(M0[j], -10.f), 10.f);
            h1[j] = v0;
            bout[j] = v0;
        }
        __syncthreads();

        // t = 1: 4-way row-split matvec
        float acc = 0.f;
        {
            const int s0 = q * 32;
            #pragma unroll 8
            for (int s2 = s0; s2 < s0 + 32; ++s2)
                acc += h1[s2] * M1[s2 * S_DIM + j];
        }
        hpart[q][j] = acc;
        __syncthreads();

        if (q == 0) {
            float v1 = hpart[0][j] + hpart[1][j] + hpart[2][j] + hpart[3][j];
            if (!(v1 >= 10.0f)) sat = 0;     // saturation must hold in every lane
            bout[S_DIM + j] = fminf(fmaxf(v1, -10.f), 10.f);
        }

        // wait for all cert blocks (acquire pairs with their release adds)
        if (tid == 0) {
            while (__hip_atomic_load(counter, __ATOMIC_ACQUIRE, __HIP_MEMORY_SCOPE_AGENT) < V_DIM)
                __builtin_amdgcn_s_sleep(2);
        }
        __syncthreads();

        // certificate: every token at t>=2 must be certified
        if (tid < L_DIM - 2) {
            if (!minok[btok[2 + tid]]) sat = 0;
        }
        __syncthreads();
        if (sat) return;                     // output already exact

        // ---- exact full scan for this batch (proven round-1 body) ----
        const int cgrp = tid & 31;
        const int rgrp = tid >> 5;

        __shared__ float  h[S_DIM];
        __shared__ float4 part4[RG][32];

        if (tid < S_DIM) h[tid] = (tid == 0) ? 1.0f : 0.0f;

        float4 cur[RPG];
        {
            const float* M = fsa + (size_t)btok[0] * (S_DIM * S_DIM);
            #pragma unroll
            for (int i = 0; i < RPG; ++i)
                cur[i] = *reinterpret_cast<const float4*>(M + (rgrp * RPG + i) * S_DIM + cgrp * 4);
        }
        __syncthreads();

        for (int t = 0; t < L_DIM; ++t) {
            const int tn = (t + 1 < L_DIM) ? (t + 1) : t;
            float4 nxt[RPG];
            {
                const float* M = fsa + (size_t)btok[tn] * (S_DIM * S_DIM);
                #pragma unroll
                for (int i = 0; i < RPG; ++i)
                    nxt[i] = *reinterpret_cast<const float4*>(M + (rgrp * RPG + i) * S_DIM + cgrp * 4);
            }

            float4 acc2 = make_float4(0.f, 0.f, 0.f, 0.f);
            #pragma unroll
            for (int i = 0; i < RPG; ++i) {
                const float hs = h[rgrp * RPG + i];
                acc2.x += hs * cur[i].x;
                acc2.y += hs * cur[i].y;
                acc2.z += hs * cur[i].z;
                acc2.w += hs * cur[i].w;
            }

            __syncthreads();
            part4[rgrp][cgrp] = acc2;
            __syncthreads();

            if (tid < S_DIM) {
                const float* pf = reinterpret_cast<const float*>(part4);
                float v = 0.f;
                #pragma unroll
                for (int g = 0; g < RG; ++g) v += pf[g * S_DIM + tid];
                v = fminf(fmaxf(v, -10.0f), 10.0f);
                bout[t * S_DIM + tid] = v;
                h[tid] = v;
            }
            __syncthreads();

            #pragma unroll
            for (int i = 0; i < RPG; ++i) cur[i] = nxt[i];
        }
    }
}

extern "C" void kernel_launch(void* const* d_in, const int* in_sizes, int n_in,
                              void* d_out, int out_size, void* d_ws, size_t ws_size,
                              hipStream_t stream) {
    const int*   tokens = (const int*)d_in[0];     // [B, L]
    // d_in[1] = lengths — unused by the reference computation
    const float* fsa    = (const float*)d_in[2];   // [V, S, S] f32
    float*       out    = (float*)d_out;           // [B, L, S] f32

    int* minok   = (int*)d_ws;                     // [V_DIM]; written before read (counter-gated)
    int* counter = minok + V_DIM;                  // [1] completion counter

    hipMemsetAsync(counter, 0, sizeof(int), stream);   // graph-capturable
    brnn_fused<<<V_DIM + B_DIM, 512, 0, stream>>>(fsa, tokens, minok, counter, out);
}

// Round 7
// 236.515 us; speedup vs baseline: 1.0098x; 1.0098x over previous
//
#include <hip/hip_runtime.h>

// BRNN integrate one-hot: h_t = clip(h_{t-1} @ fsa[tok_t], -10, 10)
// B=64 L=512 S=128 V=10000, fsa = U[0,1) (non-negative by problem spec).
//
// clip(+10) is absorbing: h2 saturates to all-10s; it stays there for every
// token whose matrix has min column-sum >= 1. fsa >= 0 => a PARTIAL column
// sum >= 1 soundly lower-bounds the full column sum. Two-stage adaptive cert
// (rows 0..6; escalate to rows 0..12 for ~2.5% of matrices).
//
// SINGLE fused kernel (grid = V+B blocks):
//   blocks 0..V-1 : spread 10.0-fill of out[:,2:,:] + adaptive cert
//                   -> minok[v] (relaxed), then RELEASE fetch_add on
//                      ctrs[v & 255]  (256-way chunked: no hot cacheline —
//                      R6's single counter cost +220 us of RMW serialization)
//   blocks V..    : exact t=0,1 head for batch b; threads 0..255 ACQUIRE-spin
//                   each on its own counter until its static quota; then check
//                   own tokens vs minok; exact full scan only on cert failure.
// Only 64 blocks wait (<< co-residency), cert blocks never wait -> forward
// progress for any dispatch order (Guideline 16: release/acquire, no ordering
// assumptions).

constexpr int S_DIM = 128;
constexpr int L_DIM = 512;
constexpr int B_DIM = 64;
constexpr int V_DIM = 10000;
constexpr int CR1   = 7;          // stage-1 certificate rows
constexpr int CR2   = 13;         // total rows after escalation
constexpr int NCTR  = 256;        // chunked completion counters
constexpr int NT    = 512;
constexpr int RG    = NT / 32;
constexpr int RPG   = S_DIM / RG;
constexpr int PER_B      = (L_DIM - 2) * S_DIM / 4;          // 16320 float4/batch
constexpr int FILL_TOTAL = PER_B * B_DIM;                    // 1044480 float4
constexpr int FPB        = (FILL_TOTAL + V_DIM - 1) / V_DIM; // 105 float4/block

typedef float f4 __attribute__((ext_vector_type(4)));

__global__ __launch_bounds__(512)
void brnn_fused(const float* __restrict__ fsa, const int* __restrict__ tokens,
                int* __restrict__ minok, int* __restrict__ ctrs,
                float* __restrict__ out) {
    const int tid = threadIdx.x;
    __shared__ float4 cpart[CR2][32];
    __shared__ float  h1[S_DIM];
    __shared__ float  hpart[4][S_DIM];
    __shared__ int    esc, bad, sat;

    if (blockIdx.x < V_DIM) {
        // ================= cert block =================
        const int v = blockIdx.x;
        if (tid == 0) { esc = 0; bad = 0; }

        // spread saturated fill: out[:, 2:, :] = 10.0 (105 contiguous float4/block)
        {
            const int i = v * FPB + tid;
            if (tid < FPB && i < FILL_TOTAL) {
                const int bb = i / PER_B;
                const int r  = i - bb * PER_B;
                f4* p = reinterpret_cast<f4*>(out + (size_t)bb * (L_DIM * S_DIM) + 2 * S_DIM);
                const f4 ten = {10.f, 10.f, 10.f, 10.f};
                __builtin_nontemporal_store(ten, p + r);
            }
        }

        const float* M = fsa + (size_t)v * (S_DIM * S_DIM);

        // stage 1: rows 0..CR1-1
        if (tid < CR1 * 32) {
            const int rg = tid >> 5;
            const int c4 = tid & 31;
            cpart[rg][c4] = *reinterpret_cast<const float4*>(M + rg * S_DIM + c4 * 4);
        }
        __syncthreads();

        float4 s;                            // live in tid<32 only
        if (tid < 32) {
            s = cpart[0][tid];
            #pragma unroll
            for (int g = 1; g < CR1; ++g) {
                float4 p = cpart[g][tid];
                s.x += p.x; s.y += p.y; s.z += p.z; s.w += p.w;
            }
            float mn = fminf(fminf(s.x, s.y), fminf(s.z, s.w));
            if (mn < 1.0f) esc = 1;          // set-to-1 race: benign
        }
        __syncthreads();

        if (esc) {                           // block-uniform branch
            if (tid < (CR2 - CR1) * 32) {
                const int rg = CR1 + (tid >> 5);
                const int c4 = tid & 31;
                cpart[rg][c4] = *reinterpret_cast<const float4*>(M + rg * S_DIM + c4 * 4);
            }
            __syncthreads();
            if (tid < 32) {
                #pragma unroll
                for (int g = CR1; g < CR2; ++g) {
                    float4 p = cpart[g][tid];
                    s.x += p.x; s.y += p.y; s.z += p.z; s.w += p.w;
                }
                float mn = fminf(fminf(s.x, s.y), fminf(s.z, s.w));
                if (mn < 1.0f) bad = 1;      // set-to-1 race: benign
            }
            __syncthreads();
        }
        if (tid == 0) {
            __hip_atomic_store(&minok[v], !bad, __ATOMIC_RELAXED, __HIP_MEMORY_SCOPE_AGENT);
            // release RMW publishes the minok store; 256-way chunked => no contention
            __hip_atomic_fetch_add(&ctrs[v & (NCTR - 1)], 1, __ATOMIC_RELEASE,
                                   __HIP_MEMORY_SCOPE_AGENT);
        }
    } else {
        // ================= head block (one batch) =================
        const int b = blockIdx.x - V_DIM;
        const int j = tid & 127;
        const int q = tid >> 7;
        const int* btok = tokens + b * L_DIM;
        float* bout = out + (size_t)b * (L_DIM * S_DIM);

        if (tid == 0) sat = 1;

        const float* M0 = fsa + (size_t)btok[0] * (S_DIM * S_DIM);
        const float* M1 = fsa + (size_t)btok[1] * (S_DIM * S_DIM);

        // t = 0: h1 = clip(row 0 of M0)
        if (q == 0) {
            float v0 = fminf(fmaxf(M0[j], -10.f), 10.f);
            h1[j] = v0;
            bout[j] = v0;
        }
        __syncthreads();

        // t = 1: 4-way row-split matvec
        float acc = 0.f;
        {
            const int s0 = q * 32;
            #pragma unroll 8
            for (int s2 = s0; s2 < s0 + 32; ++s2)
                acc += h1[s2] * M1[s2 * S_DIM + j];
        }
        hpart[q][j] = acc;
        __syncthreads();

        if (q == 0) {
            float v1 = hpart[0][j] + hpart[1][j] + hpart[2][j] + hpart[3][j];
            if (!(v1 >= 10.0f)) sat = 0;     // saturation must hold in every lane
            bout[S_DIM + j] = fminf(fmaxf(v1, -10.f), 10.f);
        }

        // wait: threads 0..NCTR-1 each spin on their own counter (acquire)
        if (tid < NCTR) {
            const int quota = 39 + (tid < (V_DIM - 39 * NCTR));   // 40 for i<16 else 39
            while (__hip_atomic_load(&ctrs[tid], __ATOMIC_ACQUIRE,
                                     __HIP_MEMORY_SCOPE_AGENT) < quota)
                __builtin_amdgcn_s_sleep(8);
        }
        __syncthreads();

        // certificate: every token at t>=2 must be certified
        if (tid < L_DIM - 2) {
            if (!minok[btok[2 + tid]]) sat = 0;
        }
        __syncthreads();
        if (sat) return;                     // output already exact

        // ---- exact full scan for this batch (proven round-1 body) ----
        const int cgrp = tid & 31;
        const int rgrp = tid >> 5;

        __shared__ float  h[S_DIM];
        __shared__ float4 part4[RG][32];

        if (tid < S_DIM) h[tid] = (tid == 0) ? 1.0f : 0.0f;

        float4 cur[RPG];
        {
            const float* M = fsa + (size_t)btok[0] * (S_DIM * S_DIM);
            #pragma unroll
            for (int i = 0; i < RPG; ++i)
                cur[i] = *reinterpret_cast<const float4*>(M + (rgrp * RPG + i) * S_DIM + cgrp * 4);
        }
        __syncthreads();

        for (int t = 0; t < L_DIM; ++t) {
            const int tn = (t + 1 < L_DIM) ? (t + 1) : t;
            float4 nxt[RPG];
            {
                const float* M = fsa + (size_t)btok[tn] * (S_DIM * S_DIM);
                #pragma unroll
                for (int i = 0; i < RPG; ++i)
                    nxt[i] = *reinterpret_cast<const float4*>(M + (rgrp * RPG + i) * S_DIM + cgrp * 4);
            }

            float4 acc2 = make_float4(0.f, 0.f, 0.f, 0.f);
            #pragma unroll
            for (int i = 0; i < RPG; ++i) {
                const float hs = h[rgrp * RPG + i];
                acc2.x += hs * cur[i].x;
                acc2.y += hs * cur[i].y;
                acc2.z += hs * cur[i].z;
                acc2.w += hs * cur[i].w;
            }

            __syncthreads();
            part4[rgrp][cgrp] = acc2;
            __syncthreads();

            if (tid < S_DIM) {
                const float* pf = reinterpret_cast<const float*>(part4);
                float v = 0.f;
                #pragma unroll
                for (int g = 0; g < RG; ++g) v += pf[g * S_DIM + tid];
                v = fminf(fmaxf(v, -10.0f), 10.0f);
                bout[t * S_DIM + tid] = v;
                h[tid] = v;
            }
            __syncthreads();

            #pragma unroll
            for (int i = 0; i < RPG; ++i) cur[i] = nxt[i];
        }
    }
}

extern "C" void kernel_launch(void* const* d_in, const int* in_sizes, int n_in,
                              void* d_out, int out_size, void* d_ws, size_t ws_size,
                              hipStream_t stream) {
    const int*   tokens = (const int*)d_in[0];     // [B, L]
    // d_in[1] = lengths — unused by the reference computation
    const float* fsa    = (const float*)d_in[2];   // [V, S, S] f32
    float*       out    = (float*)d_out;           // [B, L, S] f32

    int* minok = (int*)d_ws;                       // [V_DIM]; published via release RMW
    int* ctrs  = minok + V_DIM;                    // [NCTR] chunked completion counters

    hipMemsetAsync(ctrs, 0, NCTR * sizeof(int), stream);   // graph-capturable
    brnn_fused<<<V_DIM + B_DIM, 512, 0, stream>>>(fsa, tokens, minok, ctrs, out);
}

// Round 8
// 17.876 us; speedup vs baseline: 13.3599x; 13.2305x over previous
//
#include <hip/hip_runtime.h>

// BRNN integrate one-hot: h_t = clip(h_{t-1} @ fsa[tok_t], -10, 10)
// B=64 L=512 S=128 V=10000, fsa = U[0,1) (non-negative by problem spec).
//
// clip(+10) is absorbing: h2 saturates to all-10s; it stays there for every
// token whose matrix has min column-sum >= 1. fsa >= 0 => a PARTIAL column
// sum >= 1 soundly lower-bounds the full column sum. Two-stage adaptive cert
// (rows 0..6; escalate to rows 0..12 for ~2.5% of matrices; global
// false-fallback prob ~2e-4, and the fallback is exact anyway).
//
// R6/R7 lesson: in-kernel producer->consumer signaling via agent-scope
// release/acquire costs L2 writeback/invalidate per op on non-coherent XCD
// L2s (~220 us for 10k ops) — a kernel boundary is the cheap device-wide
// release. Two kernels:
//   k1 cert_fill_head : cert blocks (1 matrix PER WAVE, no LDS/barriers)
//                       + spread 10.0-fill + 64 head blocks (exact t=0,1)
//   k2 check_and_scan : per-batch token check vs minok; exact scan if failed

constexpr int S_DIM = 128;
constexpr int L_DIM = 512;
constexpr int B_DIM = 64;
constexpr int V_DIM = 10000;
constexpr int CR1   = 7;           // stage-1 certificate rows
constexpr int CR2   = 13;          // total rows after escalation
constexpr int WPB   = 8;           // waves per block
constexpr int CB    = V_DIM / WPB; // 1250 cert blocks
constexpr int NT    = 512;
constexpr int RG    = NT / 32;
constexpr int RPG   = S_DIM / RG;
constexpr int PER_B      = (L_DIM - 2) * S_DIM / 4;   // 16320 float4/batch
constexpr int FILL_TOTAL = PER_B * B_DIM;             // 1044480 float4

typedef float f4 __attribute__((ext_vector_type(4)));

// ---------------- k1: wave-granular cert + fill + head ----------------
__global__ __launch_bounds__(512)
void cert_fill_head(const float* __restrict__ fsa, const int* __restrict__ tokens,
                    int* __restrict__ minok, int* __restrict__ head_fail,
                    float* __restrict__ out) {
    const int tid = threadIdx.x;

    if (blockIdx.x < CB) {
        // ============ cert block: 8 waves, 1 matrix/wave, no LDS ============
        const int lane = tid & 63;
        const int wv   = tid >> 6;
        const int v    = blockIdx.x * WPB + wv;          // < V_DIM exactly

        // stage 1: rows 0..6, lane owns columns 2*lane, 2*lane+1
        const float* M = fsa + (size_t)v * (S_DIM * S_DIM) + 2 * lane;
        float2 s = make_float2(0.f, 0.f);
        #pragma unroll
        for (int r = 0; r < CR1; ++r) {
            float2 m = *reinterpret_cast<const float2*>(M + r * S_DIM);
            s.x += m.x; s.y += m.y;
        }

        // spread saturated fill: out[:, 2:, :] = 10.0 (grid-stride over cert blocks)
        {
            const f4 ten = {10.f, 10.f, 10.f, 10.f};
            f4* p = reinterpret_cast<f4*>(out + 2 * S_DIM);  // NOTE: batch offset applied below
            for (int i = blockIdx.x * 512 + tid; i < FILL_TOTAL; i += CB * 512) {
                const int bb = i / PER_B;
                const int r  = i - bb * PER_B;
                f4* q = reinterpret_cast<f4*>(out + (size_t)bb * (L_DIM * S_DIM) + 2 * S_DIM);
                __builtin_nontemporal_store(ten, q + r);
            }
            (void)p;
        }

        bool ok = (s.x >= 1.0f) && (s.y >= 1.0f);
        int allok;
        if (__all(ok)) {                     // wave-uniform
            allok = 1;
        } else {
            // escalate: rows 7..12 (full 13-row lower bound)
            #pragma unroll
            for (int r = CR1; r < CR2; ++r) {
                float2 m = *reinterpret_cast<const float2*>(M + r * S_DIM);
                s.x += m.x; s.y += m.y;
            }
            allok = __all((s.x >= 1.0f) && (s.y >= 1.0f)) ? 1 : 0;
        }
        if (lane == 0) minok[v] = allok;
    } else {
        // ============ head block: exact t=0,1 for batch b ============
        const int b = blockIdx.x - CB;
        const int j = tid & 127;
        const int q = tid >> 7;
        const int* btok = tokens + b * L_DIM;
        float* bout = out + (size_t)b * (L_DIM * S_DIM);

        __shared__ float h1[S_DIM];
        __shared__ float hpart[4][S_DIM];
        __shared__ int   flag;
        if (tid == 0) flag = 1;

        const float* M0 = fsa + (size_t)btok[0] * (S_DIM * S_DIM);
        const float* M1 = fsa + (size_t)btok[1] * (S_DIM * S_DIM);

        // t = 0: h1 = clip(row 0 of M0)
        if (q == 0) {
            float v0 = fminf(fmaxf(M0[j], -10.f), 10.f);
            h1[j] = v0;
            bout[j] = v0;
        }
        __syncthreads();

        // t = 1: 4-way row-split matvec
        float acc = 0.f;
        {
            const int s0 = q * 32;
            #pragma unroll 8
            for (int s2 = s0; s2 < s0 + 32; ++s2)
                acc += h1[s2] * M1[s2 * S_DIM + j];
        }
        hpart[q][j] = acc;
        __syncthreads();

        if (q == 0) {
            float v1 = hpart[0][j] + hpart[1][j] + hpart[2][j] + hpart[3][j];
            if (!(v1 >= 10.0f)) flag = 0;    // saturation must hold in every lane
            bout[S_DIM + j] = fminf(fmaxf(v1, -10.f), 10.f);
        }
        __syncthreads();
        if (tid == 0) head_fail[b] = !flag;
    }
}

// ---------------- k2: certificate check + gated exact scan ----------------
__global__ __launch_bounds__(NT, 2)
void check_and_scan(const int* __restrict__ tokens, const float* __restrict__ fsa,
                    const int* __restrict__ minok, const int* __restrict__ head_fail,
                    float* __restrict__ out) {
    const int b   = blockIdx.x;
    const int tid = threadIdx.x;
    const int* btok = tokens + b * L_DIM;

    __shared__ int sat;
    if (tid == 0) sat = head_fail[b] ? 0 : 1;
    __syncthreads();
    {
        const int t = 2 + tid;
        if (t < L_DIM && !minok[btok[t]]) sat = 0;
    }
    __syncthreads();
    if (sat) return;                       // certificate held: output already exact

    // ---- exact full scan for this batch (proven round-1 body) ----
    const int cgrp = tid & 31;
    const int rgrp = tid >> 5;

    __shared__ float  h[S_DIM];
    __shared__ float4 part4[RG][32];

    if (tid < S_DIM) h[tid] = (tid == 0) ? 1.0f : 0.0f;

    float* bout = out + (size_t)b * (L_DIM * S_DIM);

    float4 cur[RPG];
    {
        const float* M = fsa + (size_t)btok[0] * (S_DIM * S_DIM);
        #pragma unroll
        for (int i = 0; i < RPG; ++i)
            cur[i] = *reinterpret_cast<const float4*>(M + (rgrp * RPG + i) * S_DIM + cgrp * 4);
    }
    __syncthreads();

    for (int t = 0; t < L_DIM; ++t) {
        const int tn = (t + 1 < L_DIM) ? (t + 1) : t;
        float4 nxt[RPG];
        {
            const float* M = fsa + (size_t)btok[tn] * (S_DIM * S_DIM);
            #pragma unroll
            for (int i = 0; i < RPG; ++i)
                nxt[i] = *reinterpret_cast<const float4*>(M + (rgrp * RPG + i) * S_DIM + cgrp * 4);
        }

        float4 acc = make_float4(0.f, 0.f, 0.f, 0.f);
        #pragma unroll
        for (int i = 0; i < RPG; ++i) {
            const float hs = h[rgrp * RPG + i];
            acc.x += hs * cur[i].x;
            acc.y += hs * cur[i].y;
            acc.z += hs * cur[i].z;
            acc.w += hs * cur[i].w;
        }

        __syncthreads();
        part4[rgrp][cgrp] = acc;
        __syncthreads();

        if (tid < S_DIM) {
            const float* pf = reinterpret_cast<const float*>(part4);
            float v = 0.f;
            #pragma unroll
            for (int g = 0; g < RG; ++g) v += pf[g * S_DIM + tid];
            v = fminf(fmaxf(v, -10.0f), 10.0f);
            bout[t * S_DIM + tid] = v;
            h[tid] = v;
        }
        __syncthreads();

        #pragma unroll
        for (int i = 0; i < RPG; ++i) cur[i] = nxt[i];
    }
}

extern "C" void kernel_launch(void* const* d_in, const int* in_sizes, int n_in,
                              void* d_out, int out_size, void* d_ws, size_t ws_size,
                              hipStream_t stream) {
    const int*   tokens = (const int*)d_in[0];     // [B, L]
    // d_in[1] = lengths — unused by the reference computation
    const float* fsa    = (const float*)d_in[2];   // [V, S, S] f32
    float*       out    = (float*)d_out;           // [B, L, S] f32

    int* minok     = (int*)d_ws;                   // [V_DIM]
    int* head_fail = minok + V_DIM;                // [B_DIM]

    cert_fill_head<<<CB + B_DIM, 512, 0, stream>>>(fsa, tokens, minok, head_fail, out);
    check_and_scan<<<B_DIM, NT, 0, stream>>>(tokens, fsa, minok, head_fail, out);
}

// Round 9
// 17.180 us; speedup vs baseline: 13.9016x; 1.0405x over previous
//
#include <hip/hip_runtime.h>

// BRNN integrate one-hot: h_t = clip(h_{t-1} @ fsa[tok_t], -10, 10)
// B=64 L=512 S=128 V=10000, fsa = U[0,1) (non-negative by problem spec).
//
// clip(+10) is absorbing: h2 saturates to all-10s; it stays there for every
// token whose matrix has min column-sum >= 1. fsa >= 0 => a PARTIAL column
// sum >= 1 soundly lower-bounds the full column sum. Two-stage adaptive cert
// (rows 0..6; escalate to rows 0..12; false-fallback prob ~2e-4, and the
// fallback is exact anyway).
//
// R6/R7 lesson: agent-scope release/acquire signaling costs an L2
// writeback/invalidate per op on non-coherent XCD L2s — kernel boundary is
// the cheap device-wide release. R8->R9: 2 matrices per cert wave (14
// independent row loads in flight, not 7) + deeper fill loop for MLP.
//   k1 cert_fill_head : cert blocks (2 matrices PER WAVE, no LDS/barriers)
//                       + spread 10.0-fill + 64 head blocks (exact t=0,1)
//   k2 check_and_scan : per-batch token check vs minok; exact scan if failed

constexpr int S_DIM = 128;
constexpr int L_DIM = 512;
constexpr int B_DIM = 64;
constexpr int V_DIM = 10000;
constexpr int CR1   = 7;            // stage-1 certificate rows
constexpr int CR2   = 13;           // total rows after escalation
constexpr int WPB   = 8;            // waves per block
constexpr int MPW   = 2;            // matrices per wave
constexpr int CB    = V_DIM / (WPB * MPW);  // 625 cert blocks
constexpr int NT    = 512;
constexpr int RG    = NT / 32;
constexpr int RPG   = S_DIM / RG;
constexpr int PER_B      = (L_DIM - 2) * S_DIM / 4;   // 16320 float4/batch
constexpr int FILL_TOTAL = PER_B * B_DIM;             // 1044480 float4

typedef float f4 __attribute__((ext_vector_type(4)));

// ---------------- k1: wave-granular cert (2 mat/wave) + fill + head ----------------
__global__ __launch_bounds__(512)
void cert_fill_head(const float* __restrict__ fsa, const int* __restrict__ tokens,
                    int* __restrict__ minok, int* __restrict__ head_fail,
                    float* __restrict__ out) {
    const int tid = threadIdx.x;

    if (blockIdx.x < CB) {
        // ===== cert block: 8 waves, 2 matrices/wave, zero LDS/barriers =====
        const int lane = tid & 63;
        const int wv   = tid >> 6;
        const int v0   = (blockIdx.x * WPB + wv) * MPW;   // v0, v0+1 < V_DIM
        const int v1   = v0 + 1;

        // stage 1: rows 0..6 of BOTH matrices — 14 independent coalesced loads
        const float* Ma = fsa + (size_t)v0 * (S_DIM * S_DIM) + 2 * lane;
        const float* Mb = fsa + (size_t)v1 * (S_DIM * S_DIM) + 2 * lane;
        float2 sa = make_float2(0.f, 0.f), sb = make_float2(0.f, 0.f);
        #pragma unroll
        for (int r = 0; r < CR1; ++r) {
            float2 ma = *reinterpret_cast<const float2*>(Ma + r * S_DIM);
            float2 mb = *reinterpret_cast<const float2*>(Mb + r * S_DIM);
            sa.x += ma.x; sa.y += ma.y;
            sb.x += mb.x; sb.y += mb.y;
        }

        // spread saturated fill (issued while cert loads are in flight):
        // out[:, 2:, :] = 10.0, ~3.3 nontemporal float4 stores per thread
        {
            const f4 ten = {10.f, 10.f, 10.f, 10.f};
            for (int i = blockIdx.x * 512 + tid; i < FILL_TOTAL; i += CB * 512) {
                const int bb = i / PER_B;
                const int r  = i - bb * PER_B;
                f4* q = reinterpret_cast<f4*>(out + (size_t)bb * (L_DIM * S_DIM) + 2 * S_DIM);
                __builtin_nontemporal_store(ten, q + r);
            }
        }

        const bool okA = (sa.x >= 1.0f) && (sa.y >= 1.0f);
        const bool okB = (sb.x >= 1.0f) && (sb.y >= 1.0f);
        int allA, allB;
        if (__all(okA && okB)) {             // wave-uniform fast path (~95%)
            allA = 1; allB = 1;
        } else {
            // escalate both: rows 7..12 (full 13-row lower bound)
            #pragma unroll
            for (int r = CR1; r < CR2; ++r) {
                float2 ma = *reinterpret_cast<const float2*>(Ma + r * S_DIM);
                float2 mb = *reinterpret_cast<const float2*>(Mb + r * S_DIM);
                sa.x += ma.x; sa.y += ma.y;
                sb.x += mb.x; sb.y += mb.y;
            }
            allA = __all((sa.x >= 1.0f) && (sa.y >= 1.0f)) ? 1 : 0;
            allB = __all((sb.x >= 1.0f) && (sb.y >= 1.0f)) ? 1 : 0;
        }
        if (lane == 0) { minok[v0] = allA; minok[v1] = allB; }
    } else {
        // ============ head block: exact t=0,1 for batch b ============
        const int b = blockIdx.x - CB;
        const int j = tid & 127;
        const int q = tid >> 7;
        const int* btok = tokens + b * L_DIM;
        float* bout = out + (size_t)b * (L_DIM * S_DIM);

        __shared__ float h1[S_DIM];
        __shared__ float hpart[4][S_DIM];
        __shared__ int   flag;
        if (tid == 0) flag = 1;

        const float* M0 = fsa + (size_t)btok[0] * (S_DIM * S_DIM);
        const float* M1 = fsa + (size_t)btok[1] * (S_DIM * S_DIM);

        // t = 0: h1 = clip(row 0 of M0)
        if (q == 0) {
            float v0 = fminf(fmaxf(M0[j], -10.f), 10.f);
            h1[j] = v0;
            bout[j] = v0;
        }
        __syncthreads();

        // t = 1: 4-way row-split matvec
        float acc = 0.f;
        {
            const int s0 = q * 32;
            #pragma unroll 8
            for (int s2 = s0; s2 < s0 + 32; ++s2)
                acc += h1[s2] * M1[s2 * S_DIM + j];
        }
        hpart[q][j] = acc;
        __syncthreads();

        if (q == 0) {
            float v1 = hpart[0][j] + hpart[1][j] + hpart[2][j] + hpart[3][j];
            if (!(v1 >= 10.0f)) flag = 0;    // saturation must hold in every lane
            bout[S_DIM + j] = fminf(fmaxf(v1, -10.f), 10.f);
        }
        __syncthreads();
        if (tid == 0) head_fail[b] = !flag;
    }
}

// ---------------- k2: certificate check + gated exact scan ----------------
__global__ __launch_bounds__(NT, 2)
void check_and_scan(const int* __restrict__ tokens, const float* __restrict__ fsa,
                    const int* __restrict__ minok, const int* __restrict__ head_fail,
                    float* __restrict__ out) {
    const int b   = blockIdx.x;
    const int tid = threadIdx.x;
    const int* btok = tokens + b * L_DIM;

    __shared__ int sat;
    if (tid == 0) sat = head_fail[b] ? 0 : 1;
    __syncthreads();
    {
        const int t = 2 + tid;
        if (t < L_DIM && !minok[btok[t]]) sat = 0;
    }
    __syncthreads();
    if (sat) return;                       // certificate held: output already exact

    // ---- exact full scan for this batch (proven round-1 body) ----
    const int cgrp = tid & 31;
    const int rgrp = tid >> 5;

    __shared__ float  h[S_DIM];
    __shared__ float4 part4[RG][32];

    if (tid < S_DIM) h[tid] = (tid == 0) ? 1.0f : 0.0f;

    float* bout = out + (size_t)b * (L_DIM * S_DIM);

    float4 cur[RPG];
    {
        const float* M = fsa + (size_t)btok[0] * (S_DIM * S_DIM);
        #pragma unroll
        for (int i = 0; i < RPG; ++i)
            cur[i] = *reinterpret_cast<const float4*>(M + (rgrp * RPG + i) * S_DIM + cgrp * 4);
    }
    __syncthreads();

    for (int t = 0; t < L_DIM; ++t) {
        const int tn = (t + 1 < L_DIM) ? (t + 1) : t;
        float4 nxt[RPG];
        {
            const float* M = fsa + (size_t)btok[tn] * (S_DIM * S_DIM);
            #pragma unroll
            for (int i = 0; i < RPG; ++i)
                nxt[i] = *reinterpret_cast<const float4*>(M + (rgrp * RPG + i) * S_DIM + cgrp * 4);
        }

        float4 acc = make_float4(0.f, 0.f, 0.f, 0.f);
        #pragma unroll
        for (int i = 0; i < RPG; ++i) {
            const float hs = h[rgrp * RPG + i];
            acc.x += hs * cur[i].x;
            acc.y += hs * cur[i].y;
            acc.z += hs * cur[i].z;
            acc.w += hs * cur[i].w;
        }

        __syncthreads();
        part4[rgrp][cgrp] = acc;
        __syncthreads();

        if (tid < S_DIM) {
            const float* pf = reinterpret_cast<const float*>(part4);
            float v = 0.f;
            #pragma unroll
            for (int g = 0; g < RG; ++g) v += pf[g * S_DIM + tid];
            v = fminf(fmaxf(v, -10.0f), 10.0f);
            bout[t * S_DIM + tid] = v;
            h[tid] = v;
        }
        __syncthreads();

        #pragma unroll
        for (int i = 0; i < RPG; ++i) cur[i] = nxt[i];
    }
}

extern "C" void kernel_launch(void* const* d_in, const int* in_sizes, int n_in,
                              void* d_out, int out_size, void* d_ws, size_t ws_size,
                              hipStream_t stream) {
    const int*   tokens = (const int*)d_in[0];     // [B, L]
    // d_in[1] = lengths — unused by the reference computation
    const float* fsa    = (const float*)d_in[2];   // [V, S, S] f32
    float*       out    = (float*)d_out;           // [B, L, S] f32

    int* minok     = (int*)d_ws;                   // [V_DIM]
    int* head_fail = minok + V_DIM;                // [B_DIM]

    cert_fill_head<<<CB + B_DIM, 512, 0, stream>>>(fsa, tokens, minok, head_fail, out);
    check_and_scan<<<B_DIM, NT, 0, stream>>>(tokens, fsa, minok, head_fail, out);
}

// Round 10
// 17.080 us; speedup vs baseline: 13.9828x; 1.0058x over previous
//
#include <hip/hip_runtime.h>

// BRNN integrate one-hot: h_t = clip(h_{t-1} @ fsa[tok_t], -10, 10)
// B=64 L=512 S=128 V=10000, fsa = U[0,1) (non-negative by problem spec).
//
// clip(+10) is absorbing: h2 saturates to all-10s; it stays there for every
// token whose matrix has min column-sum >= 1. fsa >= 0 => a PARTIAL column
// sum >= 1 soundly lower-bounds the full column sum. Two-stage adaptive cert
// (rows 0..6; escalate to rows 0..12; false-fallback prob ~2e-4, and the
// fallback is exact anyway). Cert traffic is information-theoretically tight:
// E[rows until all 128 colsums >= 1] ~ 7 for U[0,1) entries.
//
// R10: homogeneous streams — k1 grid = 335 pure-fill blocks + 625 pure-cert
// blocks (2 matrices/wave, 14 loads in flight, no LDS/barriers) + 64 head
// blocks = 1024 blocks = 4/CU exactly. Kernel boundary (not agent-scope
// atomics — R6/R7 lesson) publishes minok to k2.
//   k2 check_and_scan : per-batch token check vs minok; exact scan if failed

constexpr int S_DIM = 128;
constexpr int L_DIM = 512;
constexpr int B_DIM = 64;
constexpr int V_DIM = 10000;
constexpr int CR1   = 7;            // stage-1 certificate rows
constexpr int CR2   = 13;           // total rows after escalation
constexpr int WPB   = 8;            // waves per block
constexpr int MPW   = 2;            // matrices per wave
constexpr int FB    = 335;          // dedicated fill blocks
constexpr int CERTB = V_DIM / (WPB * MPW);  // 625 cert blocks
constexpr int NT    = 512;
constexpr int RG    = NT / 32;
constexpr int RPG   = S_DIM / RG;
constexpr int PER_B      = (L_DIM - 2) * S_DIM / 4;   // 16320 float4/batch
constexpr int FILL_TOTAL = PER_B * B_DIM;             // 1044480 float4

typedef float f4 __attribute__((ext_vector_type(4)));

// ---------------- k1: fill blocks + cert blocks + head blocks ----------------
__global__ __launch_bounds__(512)
void cert_fill_head(const float* __restrict__ fsa, const int* __restrict__ tokens,
                    int* __restrict__ minok, int* __restrict__ head_fail,
                    float* __restrict__ out) {
    const int tid = threadIdx.x;

    if (blockIdx.x < FB) {
        // ===== pure fill block: out[:, 2:, :] = 10.0, nontemporal stream =====
        const f4 ten = {10.f, 10.f, 10.f, 10.f};
        for (int i = blockIdx.x * 512 + tid; i < FILL_TOTAL; i += FB * 512) {
            const int bb = i / PER_B;
            const int r  = i - bb * PER_B;
            f4* q = reinterpret_cast<f4*>(out + (size_t)bb * (L_DIM * S_DIM) + 2 * S_DIM);
            __builtin_nontemporal_store(ten, q + r);
        }
    } else if (blockIdx.x < FB + CERTB) {
        // ===== cert block: 8 waves, 2 matrices/wave, zero LDS/barriers =====
        const int lane = tid & 63;
        const int wv   = tid >> 6;
        const int v0   = ((blockIdx.x - FB) * WPB + wv) * MPW;   // v0, v0+1 < V_DIM
        const int v1   = v0 + 1;

        // stage 1: rows 0..6 of BOTH matrices — 14 independent coalesced loads
        const float* Ma = fsa + (size_t)v0 * (S_DIM * S_DIM) + 2 * lane;
        const float* Mb = fsa + (size_t)v1 * (S_DIM * S_DIM) + 2 * lane;
        float2 sa = make_float2(0.f, 0.f), sb = make_float2(0.f, 0.f);
        #pragma unroll
        for (int r = 0; r < CR1; ++r) {
            float2 ma = *reinterpret_cast<const float2*>(Ma + r * S_DIM);
            float2 mb = *reinterpret_cast<const float2*>(Mb + r * S_DIM);
            sa.x += ma.x; sa.y += ma.y;
            sb.x += mb.x; sb.y += mb.y;
        }

        const bool okA = (sa.x >= 1.0f) && (sa.y >= 1.0f);
        const bool okB = (sb.x >= 1.0f) && (sb.y >= 1.0f);
        int allA, allB;
        if (__all(okA && okB)) {             // wave-uniform fast path (~95%)
            allA = 1; allB = 1;
        } else {
            // escalate both: rows 7..12 (full 13-row lower bound)
            #pragma unroll
            for (int r = CR1; r < CR2; ++r) {
                float2 ma = *reinterpret_cast<const float2*>(Ma + r * S_DIM);
                float2 mb = *reinterpret_cast<const float2*>(Mb + r * S_DIM);
                sa.x += ma.x; sa.y += ma.y;
                sb.x += mb.x; sb.y += mb.y;
            }
            allA = __all((sa.x >= 1.0f) && (sa.y >= 1.0f)) ? 1 : 0;
            allB = __all((sb.x >= 1.0f) && (sb.y >= 1.0f)) ? 1 : 0;
        }
        if (lane == 0) { minok[v0] = allA; minok[v1] = allB; }
    } else {
        // ============ head block: exact t=0,1 for batch b ============
        const int b = blockIdx.x - (FB + CERTB);
        const int j = tid & 127;
        const int q = tid >> 7;
        const int* btok = tokens + b * L_DIM;
        float* bout = out + (size_t)b * (L_DIM * S_DIM);

        __shared__ float h1[S_DIM];
        __shared__ float hpart[4][S_DIM];
        __shared__ int   flag;
        if (tid == 0) flag = 1;

        const float* M0 = fsa + (size_t)btok[0] * (S_DIM * S_DIM);
        const float* M1 = fsa + (size_t)btok[1] * (S_DIM * S_DIM);

        // t = 0: h1 = clip(row 0 of M0)
        if (q == 0) {
            float v0 = fminf(fmaxf(M0[j], -10.f), 10.f);
            h1[j] = v0;
            bout[j] = v0;
        }
        __syncthreads();

        // t = 1: 4-way row-split matvec
        float acc = 0.f;
        {
            const int s0 = q * 32;
            #pragma unroll 8
            for (int s2 = s0; s2 < s0 + 32; ++s2)
                acc += h1[s2] * M1[s2 * S_DIM + j];
        }
        hpart[q][j] = acc;
        __syncthreads();

        if (q == 0) {
            float v1 = hpart[0][j] + hpart[1][j] + hpart[2][j] + hpart[3][j];
            if (!(v1 >= 10.0f)) flag = 0;    // saturation must hold in every lane
            bout[S_DIM + j] = fminf(fmaxf(v1, -10.f), 10.f);
        }
        __syncthreads();
        if (tid == 0) head_fail[b] = !flag;
    }
}

// ---------------- k2: certificate check + gated exact scan ----------------
__global__ __launch_bounds__(NT, 2)
void check_and_scan(const int* __restrict__ tokens, const float* __restrict__ fsa,
                    const int* __restrict__ minok, const int* __restrict__ head_fail,
                    float* __restrict__ out) {
    const int b   = blockIdx.x;
    const int tid = threadIdx.x;
    const int* btok = tokens + b * L_DIM;

    __shared__ int sat;
    if (tid == 0) sat = head_fail[b] ? 0 : 1;
    __syncthreads();
    {
        const int t = 2 + tid;
        if (t < L_DIM && !minok[btok[t]]) sat = 0;
    }
    __syncthreads();
    if (sat) return;                       // certificate held: output already exact

    // ---- exact full scan for this batch (proven round-1 body) ----
    const int cgrp = tid & 31;
    const int rgrp = tid >> 5;

    __shared__ float  h[S_DIM];
    __shared__ float4 part4[RG][32];

    if (tid < S_DIM) h[tid] = (tid == 0) ? 1.0f : 0.0f;

    float* bout = out + (size_t)b * (L_DIM * S_DIM);

    float4 cur[RPG];
    {
        const float* M = fsa + (size_t)btok[0] * (S_DIM * S_DIM);
        #pragma unroll
        for (int i = 0; i < RPG; ++i)
            cur[i] = *reinterpret_cast<const float4*>(M + (rgrp * RPG + i) * S_DIM + cgrp * 4);
    }
    __syncthreads();

    for (int t = 0; t < L_DIM; ++t) {
        const int tn = (t + 1 < L_DIM) ? (t + 1) : t;
        float4 nxt[RPG];
        {
            const float* M = fsa + (size_t)btok[tn] * (S_DIM * S_DIM);
            #pragma unroll
            for (int i = 0; i < RPG; ++i)
                nxt[i] = *reinterpret_cast<const float4*>(M + (rgrp * RPG + i) * S_DIM + cgrp * 4);
        }

        float4 acc = make_float4(0.f, 0.f, 0.f, 0.f);
        #pragma unroll
        for (int i = 0; i < RPG; ++i) {
            const float hs = h[rgrp * RPG + i];
            acc.x += hs * cur[i].x;
            acc.y += hs * cur[i].y;
            acc.z += hs * cur[i].z;
            acc.w += hs * cur[i].w;
        }

        __syncthreads();
        part4[rgrp][cgrp] = acc;
        __syncthreads();

        if (tid < S_DIM) {
            const float* pf = reinterpret_cast<const float*>(part4);
            float v = 0.f;
            #pragma unroll
            for (int g = 0; g < RG; ++g) v += pf[g * S_DIM + tid];
            v = fminf(fmaxf(v, -10.0f), 10.0f);
            bout[t * S_DIM + tid] = v;
            h[tid] = v;
        }
        __syncthreads();

        #pragma unroll
        for (int i = 0; i < RPG; ++i) cur[i] = nxt[i];
    }
}

extern "C" void kernel_launch(void* const* d_in, const int* in_sizes, int n_in,
                              void* d_out, int out_size, void* d_ws, size_t ws_size,
                              hipStream_t stream) {
    const int*   tokens = (const int*)d_in[0];     // [B, L]
    // d_in[1] = lengths — unused by the reference computation
    const float* fsa    = (const float*)d_in[2];   // [V, S, S] f32
    float*       out    = (float*)d_out;           // [B, L, S] f32

    int* minok     = (int*)d_ws;                   // [V_DIM]
    int* head_fail = minok + V_DIM;                // [B_DIM]

    cert_fill_head<<<FB + CERTB + B_DIM, 512, 0, stream>>>(fsa, tokens, minok, head_fail, out);
    check_and_scan<<<B_DIM, NT, 0, stream>>>(tokens, fsa, minok, head_fail, out);
}